// Round 7
// baseline (274.024 us; speedup 1.0000x reference)
//
#include <hip/hip_runtime.h>

// DilatedAttention: b=2,h=16,s=8192,d=64; W=[4,8,16], R=[1,2,4] -> L=4 for all
// groups. A 32-position span is self-contained for all three groups. fp32.
//
// V8 = V7's schedule (NS=8 spans/block to amortize per-block fixed cost;
// double-buffered lv/pl; ONE __syncthreads per span; V(i+1) prefetch issued
// before phase 2's ~2k-cycle dot chain) with the SPILL REMOVED:
//   V7's lambda body with float4& reference outs blocked SROA -> ping-pong
//   regs lived in scratch (WRITE_SIZE 64->152 MB, FETCH +76 MB, VALUBusy 8%).
//   V8 uses plain named float4 P0,P1 prefetch regs + straight-line loop --
//   no lambdas, no reference params, no arrays. The copy C=P at loop top is
//   a register rename that also places the vmcnt wait correctly.
// V7 despite the spill sustained 2.39 TB/s (vs 1.8 for all short-block
// variants) -- amortization works; clean traffic at that rate => ~70 us.
//
// Race audit (1 barrier/span, 2 slots): thread A's phase3(i-1) reads of slot
// (i-1)&1 complete before A reaches sync(i); any thread's writes to slot
// (i+1)&1 happen after it passes sync(i). sync(i) orders them. pl likewise.

#define SPAN 32
#define D    64
#define S_SEQ 8192
#define NS   8

__device__ __forceinline__ void acc_group(float4& acc, const float* lvs,
                                          const float4 pr, float wg,
                                          int kb, int stride, int dd) {
    float p0 = pr.x * wg;
    float p1 = pr.y * wg;
    float p2 = pr.z * wg;
    float p3 = pr.w * wg;
    const float* vr = &lvs[kb * D + dd];
    float4 v0 = *(const float4*)(vr);
    float4 v1 = *(const float4*)(vr + stride * D);
    float4 v2 = *(const float4*)(vr + 2 * stride * D);
    float4 v3 = *(const float4*)(vr + 3 * stride * D);
    acc.x += p0 * v0.x + p1 * v1.x + p2 * v2.x + p3 * v3.x;
    acc.y += p0 * v0.y + p1 * v1.y + p2 * v2.y + p3 * v3.y;
    acc.z += p0 * v0.z + p1 * v1.z + p2 * v2.z + p3 * v3.z;
    acc.w += p0 * v0.w + p1 * v1.w + p2 * v2.w + p3 * v3.w;
}

__global__ __launch_bounds__(256, 8) void dilated_attn_kernel(
    const float* __restrict__ q,
    const float* __restrict__ k,
    const float* __restrict__ v,
    const float* __restrict__ alpha,
    float* __restrict__ out) {
    __shared__ __align__(16) float lv[2][SPAN * D];   // 2 x 8 KB, unpadded
    __shared__ __align__(16) float pl[2][224];        // 2 x (56 rows x 4)

    const int tid = threadIdx.x;
    const int chunks = (S_SEQ / SPAN) / NS;           // 32 chunks per bh
    const int bh = blockIdx.x / chunks;
    const int chunk = blockIdx.x % chunks;
    const long long base = (long long)bh * S_SEQ + (long long)chunk * (NS * SPAN);

    // softmax(alpha): once per 8 spans
    float a0 = alpha[0];
    float a1 = alpha[1];
    float a2 = alpha[2];
    float am = fmaxf(a0, fmaxf(a1, a2));
    float e0 = __expf(a0 - am), e1 = __expf(a1 - am), e2 = __expf(a2 - am);
    float inv = 1.0f / (e0 + e1 + e2);
    const float w0 = e0 * inv, w1 = e1 * inv, w2 = e2 * inv;

    // staging geometry: 2 rows/thread, coalesced float4
    const int r0 = tid >> 4;        // 0..15
    const int r1 = r0 + 16;         // 16..31
    const int c4 = tid & 15;        // float4 chunk within row
    const float4* v4p = (const float4*)v;

    // prefetch registers: PLAIN NAMED LOCALS (no lambda, no array, no ref)
    float4 P0 = v4p[(base + r0) * (D / 4) + c4];
    float4 P1 = v4p[(base + r1) * (D / 4) + c4];

#pragma unroll 1
    for (int i = 0; i < NS; ++i) {
        const int sl = i & 1;
        const long long rowbase = base + (long long)i * SPAN;

        // take ownership of span-i's V (register rename; forces the wait on
        // the prefetch issued one full span ago -- long since returned)
        float4 C0 = P0;
        float4 C1 = P1;

        // issue V(i+1) prefetch BEFORE phase 2: its HBM latency hides under
        // the ~2k-cycle dot chain below
        if (i + 1 < NS) {
            const long long rbn = rowbase + SPAN;
            P0 = v4p[(rbn + r0) * (D / 4) + c4];
            P1 = v4p[(rbn + r1) * (D / 4) + c4];
        }

        // ---- phase 2: 224 scores = 56 query rows x 4 keys, q/k from GLOBAL
        // (quad-siblings share the same 16B chunk -> L1 broadcast) ----
        if (tid < 224) {
            const int row = tid >> 2;  // 0..55
            const int j   = tid & 3;
            int w, r, win, ii;
            if (row < 32)      { w = 4;  r = 1; win = row >> 2;        ii = row & 3; }
            else if (row < 48) { w = 8;  r = 2; win = (row - 32) >> 2; ii = (row - 32) & 3; }
            else               { w = 16; r = 4; win = (row - 48) >> 2; ii = (row - 48) & 3; }
            const int pq = win * w + ii * r;
            const int pk = win * w + j * r;
            const float4* qg = (const float4*)q + (rowbase + pq) * (D / 4);
            const float4* kg = (const float4*)k + (rowbase + pk) * (D / 4);
            float acc4[4] = {0.f, 0.f, 0.f, 0.f};  // 4 chains -> ILP
#pragma unroll
            for (int c = 0; c < 16; ++c) {
                float4 a = qg[c];
                float4 b = kg[c];
                acc4[c & 3] += a.x * b.x + a.y * b.y + a.z * b.z + a.w * b.w;
            }
            float s = (acc4[0] + acc4[1]) + (acc4[2] + acc4[3]);
            s *= 0.125f;  // d^-0.5
            float m = fmaxf(s, __shfl_xor(s, 1));
            m = fmaxf(m, __shfl_xor(m, 2));
            float p = __expf(s - m);
            float sum = p + __shfl_xor(p, 1);
            sum += __shfl_xor(sum, 2);
            pl[sl][tid] = p / sum;   // pl[row*4 + j]
        }

        // ---- stage V(i) -> LDS slot sl ----
        *(float4*)&lv[sl][r0 * D + c4 * 4] = C0;
        *(float4*)&lv[sl][r1 * D + c4 * 4] = C1;

        __syncthreads();   // the ONLY barrier this span

        // ---- phase 3: PV + mix. Wave wv handles pos ≡ wv (mod 4). ----
        const float* lvs = &lv[sl][0];
        const float* pls = &pl[sl][0];
        const int wv   = tid >> 6;        // 0..3
        const int lane = tid & 63;
        const int dd   = (lane & 15) << 2;
        const int psub = lane >> 4;       // 0..3
#pragma unroll
        for (int s2 = 0; s2 < 2; ++s2) {
            const int pos = wv + 16 * s2 + 4 * psub;   // pos % 4 == wv
            float4 acc = make_float4(0.f, 0.f, 0.f, 0.f);

            {   // group 0 (w=4, r=1): every position; prob row == pos
                float4 pr = *(const float4*)&pls[pos * 4];
                acc_group(acc, lvs, pr, w0, pos & ~3, 1, dd);
            }
            if ((wv & 1) == 0) {  // group 1 (w=8, r=2): pos even
                const int prow = 32 + ((pos >> 3) << 2) + ((pos & 7) >> 1);
                float4 pr = *(const float4*)&pls[prow * 4];
                acc_group(acc, lvs, pr, w1, pos & ~7, 2, dd);
            }
            if (wv == 0) {        // group 2 (w=16, r=4): pos % 4 == 0
                const int prow = 48 + ((pos >> 4) << 2) + ((pos & 15) >> 2);
                float4 pr = *(const float4*)&pls[prow * 4];
                acc_group(acc, lvs, pr, w2, pos & ~15, 4, dd);
            }

            *(float4*)&out[(rowbase + pos) * D + dd] = acc;
        }
        // no trailing barrier: next span writes the OTHER slot; the
        // slot-reuse hazard is ordered by the next iteration's sync.
    }
}

extern "C" void kernel_launch(void* const* d_in, const int* in_sizes, int n_in,
                              void* d_out, int out_size, void* d_ws, size_t ws_size,
                              hipStream_t stream) {
    const float* q = (const float*)d_in[0];
    const float* k = (const float*)d_in[1];
    const float* v = (const float*)d_in[2];
    const float* alpha = (const float*)d_in[3];
    float* out = (float*)d_out;

    const int BH = in_sizes[0] / (S_SEQ * D);                 // b*h = 32
    dim3 grid(BH * ((S_SEQ / SPAN) / NS));                    // 1024 blocks
    dim3 block(256);
    hipLaunchKernelGGL(dilated_attn_kernel, grid, block, 0, stream,
                       q, k, v, alpha, out);
}

// Round 8
// 249.699 us; speedup vs baseline: 1.0974x; 1.0974x over previous
//
#include <hip/hip_runtime.h>

// DilatedAttention: b=2,h=16,s=8192,d=64; W=[4,8,16], R=[1,2,4] -> L=4 for all
// groups. A 32-position span is self-contained for all three groups. fp32.
//
// V9 = V3's verified clean per-span body (V loaded into plain locals at the
// TOP of the span, consumed after phase 2 -- latency hides under the
// ~2k-cycle dot chain; VGPR 28, zero scratch, exact write traffic) wrapped
// in the NS=8 span loop (per-block fixed cost amortized; V7/V8 showed long
// blocks sustain 2.2-2.4 TB/s vs 1.8 for 8192 short blocks).
// The cross-span register prefetch is REMOVED: V7 (lambda refs) and V8
// (loop-carried conditional float4 phi across __syncthreads) both forced
// ~67 MB/dir of scratch spill traffic. Same-iteration load needs no
// loop-carried vector state at all.
//
// Race audit (1 barrier/span, 2 slots): phase3(i) reads lv[sl]/pl[sl] after
// sync(i); writes to slot sl^1 happen in iteration i+1 before sync(i+1).
// Any thread's reads of slot sl^1 from phase3(i-1) completed before it
// reached sync(i), which precedes iteration i+1's writes. Safe.

#define SPAN 32
#define D    64
#define S_SEQ 8192
#define NS   8

__device__ __forceinline__ void acc_group(float4& acc, const float* lvs,
                                          const float4 pr, float wg,
                                          int kb, int stride, int dd) {
    float p0 = pr.x * wg;
    float p1 = pr.y * wg;
    float p2 = pr.z * wg;
    float p3 = pr.w * wg;
    const float* vr = &lvs[kb * D + dd];
    float4 v0 = *(const float4*)(vr);
    float4 v1 = *(const float4*)(vr + stride * D);
    float4 v2 = *(const float4*)(vr + 2 * stride * D);
    float4 v3 = *(const float4*)(vr + 3 * stride * D);
    acc.x += p0 * v0.x + p1 * v1.x + p2 * v2.x + p3 * v3.x;
    acc.y += p0 * v0.y + p1 * v1.y + p2 * v2.y + p3 * v3.y;
    acc.z += p0 * v0.z + p1 * v1.z + p2 * v2.z + p3 * v3.z;
    acc.w += p0 * v0.w + p1 * v1.w + p2 * v2.w + p3 * v3.w;
}

__global__ __launch_bounds__(256, 8) void dilated_attn_kernel(
    const float* __restrict__ q,
    const float* __restrict__ k,
    const float* __restrict__ v,
    const float* __restrict__ alpha,
    float* __restrict__ out) {
    __shared__ __align__(16) float lv[2][SPAN * D];   // 2 x 8 KB, unpadded
    __shared__ __align__(16) float pl[2][224];        // 2 x (56 rows x 4)

    const int tid = threadIdx.x;
    const int chunks = (S_SEQ / SPAN) / NS;           // 32 chunks per bh
    const int bh = blockIdx.x / chunks;
    const int chunk = blockIdx.x % chunks;
    const long long base = (long long)bh * S_SEQ + (long long)chunk * (NS * SPAN);

    // softmax(alpha): once per 8 spans
    float a0 = alpha[0];
    float a1 = alpha[1];
    float a2 = alpha[2];
    float am = fmaxf(a0, fmaxf(a1, a2));
    float e0 = __expf(a0 - am), e1 = __expf(a1 - am), e2 = __expf(a2 - am);
    float inv = 1.0f / (e0 + e1 + e2);
    const float w0 = e0 * inv, w1 = e1 * inv, w2 = e2 * inv;

    // staging geometry: 2 rows/thread, coalesced float4
    const int r0 = tid >> 4;        // 0..15
    const int r1 = r0 + 16;         // 16..31
    const int c4 = tid & 15;        // float4 chunk within row
    const float4* v4p = (const float4*)v;

#pragma unroll 1
    for (int i = 0; i < NS; ++i) {
        const int sl = i & 1;
        const long long rowbase = base + (long long)i * SPAN;

        // ---- V(i) load, SAME iteration (V3 pattern: zero loop-carried
        // vector state -> no spill). Latency hides under phase 2 below. ----
        float4 C0 = v4p[(rowbase + r0) * (D / 4) + c4];
        float4 C1 = v4p[(rowbase + r1) * (D / 4) + c4];

        // ---- phase 2: 224 scores = 56 query rows x 4 keys, q/k from GLOBAL
        // (quad-siblings share the same 16B chunk -> L1 broadcast) ----
        if (tid < 224) {
            const int row = tid >> 2;  // 0..55
            const int j   = tid & 3;
            int w, r, win, ii;
            if (row < 32)      { w = 4;  r = 1; win = row >> 2;        ii = row & 3; }
            else if (row < 48) { w = 8;  r = 2; win = (row - 32) >> 2; ii = (row - 32) & 3; }
            else               { w = 16; r = 4; win = (row - 48) >> 2; ii = (row - 48) & 3; }
            const int pq = win * w + ii * r;
            const int pk = win * w + j * r;
            const float4* qg = (const float4*)q + (rowbase + pq) * (D / 4);
            const float4* kg = (const float4*)k + (rowbase + pk) * (D / 4);
            float acc4[4] = {0.f, 0.f, 0.f, 0.f};  // 4 chains -> ILP
#pragma unroll
            for (int c = 0; c < 16; ++c) {
                float4 a = qg[c];
                float4 b = kg[c];
                acc4[c & 3] += a.x * b.x + a.y * b.y + a.z * b.z + a.w * b.w;
            }
            float s = (acc4[0] + acc4[1]) + (acc4[2] + acc4[3]);
            s *= 0.125f;  // d^-0.5
            float m = fmaxf(s, __shfl_xor(s, 1));
            m = fmaxf(m, __shfl_xor(m, 2));
            float p = __expf(s - m);
            float sum = p + __shfl_xor(p, 1);
            sum += __shfl_xor(sum, 2);
            pl[sl][tid] = p / sum;   // pl[row*4 + j]
        }

        // ---- stage V(i) -> LDS slot sl (loads returned during phase 2) ----
        *(float4*)&lv[sl][r0 * D + c4 * 4] = C0;
        *(float4*)&lv[sl][r1 * D + c4 * 4] = C1;

        __syncthreads();   // the ONLY barrier this span

        // ---- phase 3: PV + mix. Wave wv handles pos ≡ wv (mod 4). ----
        const float* lvs = &lv[sl][0];
        const float* pls = &pl[sl][0];
        const int wv   = tid >> 6;        // 0..3
        const int lane = tid & 63;
        const int dd   = (lane & 15) << 2;
        const int psub = lane >> 4;       // 0..3
#pragma unroll
        for (int s2 = 0; s2 < 2; ++s2) {
            const int pos = wv + 16 * s2 + 4 * psub;   // pos % 4 == wv
            float4 acc = make_float4(0.f, 0.f, 0.f, 0.f);

            {   // group 0 (w=4, r=1): every position; prob row == pos
                float4 pr = *(const float4*)&pls[pos * 4];
                acc_group(acc, lvs, pr, w0, pos & ~3, 1, dd);
            }
            if ((wv & 1) == 0) {  // group 1 (w=8, r=2): pos even
                const int prow = 32 + ((pos >> 3) << 2) + ((pos & 7) >> 1);
                float4 pr = *(const float4*)&pls[prow * 4];
                acc_group(acc, lvs, pr, w1, pos & ~7, 2, dd);
            }
            if (wv == 0) {        // group 2 (w=16, r=4): pos % 4 == 0
                const int prow = 48 + ((pos >> 4) << 2) + ((pos & 15) >> 2);
                float4 pr = *(const float4*)&pls[prow * 4];
                acc_group(acc, lvs, pr, w2, pos & ~15, 4, dd);
            }

            *(float4*)&out[(rowbase + pos) * D + dd] = acc;
        }
        // no trailing barrier: next span writes the OTHER slot; the
        // slot-reuse hazard is ordered by the next iteration's sync.
    }
}

extern "C" void kernel_launch(void* const* d_in, const int* in_sizes, int n_in,
                              void* d_out, int out_size, void* d_ws, size_t ws_size,
                              hipStream_t stream) {
    const float* q = (const float*)d_in[0];
    const float* k = (const float*)d_in[1];
    const float* v = (const float*)d_in[2];
    const float* alpha = (const float*)d_in[3];
    float* out = (float*)d_out;

    const int BH = in_sizes[0] / (S_SEQ * D);                 // b*h = 32
    dim3 grid(BH * ((S_SEQ / SPAN) / NS));                    // 1024 blocks
    dim3 block(256);
    hipLaunchKernelGGL(dilated_attn_kernel, grid, block, 0, stream,
                       q, k, v, alpha, out);
}